// Round 7
// baseline (609.788 us; speedup 1.0000x reference)
//
#include <hip/hip_runtime.h>
#include <math.h>
#include <float.h>

#define BLK 256
#define K3_BLOCKS 1024   // 4 blocks/CU resident (VGPR ~100 tier) -> persistent waves

// ---------------------------------------------------------------------------
// K0: fast exclusive scan of both count arrays. One block, 1024 threads.
// ---------------------------------------------------------------------------
__device__ __forceinline__ void scan_one(const int* __restrict__ cnt, int n,
                                         int* __restrict__ starts, int* wsum)
{
    const int t = threadIdx.x;
    const int chunk = (n + 1023) / 1024;
    const int base = t * chunk;

    int sum = 0;
    for (int k = 0; k < chunk; k++) {
        int idx = base + k;
        if (idx < n) sum += cnt[idx];
    }

    const int lane = t & 63, wid = t >> 6;
    int v = sum;
#pragma unroll
    for (int off = 1; off < 64; off <<= 1) {
        int y = __shfl_up(v, off);
        if (lane >= off) v += y;
    }
    if (lane == 63) wsum[wid] = v;
    __syncthreads();
    if (wid == 0) {
        int w = (lane < 16) ? wsum[lane] : 0;
#pragma unroll
        for (int off = 1; off < 16; off <<= 1) {
            int y = __shfl_up(w, off);
            if (lane >= off) w += y;
        }
        if (lane < 16) wsum[lane] = w;
    }
    __syncthreads();

    int thr_excl = ((wid > 0) ? wsum[wid - 1] : 0) + v - sum;
    int run = thr_excl;
    for (int k = 0; k < chunk; k++) {
        int idx = base + k;
        if (idx < n) { starts[idx] = run; run += cnt[idx]; }
    }
    if (t == 0) starts[n] = wsum[15];
    __syncthreads();
}

__global__ __launch_bounds__(1024) void scan2_kernel(
    const int* __restrict__ dag_cnt, int nd,
    const int* __restrict__ obs_cnt, int no,
    int* __restrict__ dag_starts, int* __restrict__ obs_starts)
{
    __shared__ int wsum[16];
    scan_one(dag_cnt, nd, dag_starts, wsum);
    scan_one(obs_cnt, no, obs_starts, wsum);
}

// ---------------------------------------------------------------------------
// K1: expand segment ids to per-node arrays (one block per segment).
// ---------------------------------------------------------------------------
__global__ __launch_bounds__(128) void expand_ids_kernel(
    const int* __restrict__ dag_starts, int nd,
    const int* __restrict__ obs_starts, int no,
    int* __restrict__ dag_ids, int* __restrict__ obs_ids)
{
    int seg = blockIdx.x;
    if (seg < nd) {
        int s = dag_starts[seg], e = dag_starts[seg + 1];
        for (int i = s + threadIdx.x; i < e; i += 128) dag_ids[i] = seg;
    } else {
        int g = seg - nd;
        int s = obs_starts[g], e = obs_starts[g + 1];
        for (int i = s + threadIdx.x; i < e; i += 128) obs_ids[i] = g;
    }
}

// ---------------------------------------------------------------------------
// K2: per-segment layer-1 partials (dag rows 37..68 no bias; glob rows 69..100 +b1).
// ---------------------------------------------------------------------------
__global__ __launch_bounds__(256) void seg_h1_kernel(
    const float* __restrict__ dag_sum, int nd,
    const float* __restrict__ glob_sum, int no,
    const float* __restrict__ W1, const float* __restrict__ b1,
    float* __restrict__ dag_h1, float* __restrict__ glob_h1)
{
    __shared__ float Wd[32 * 32];
    __shared__ float Wg[32 * 32];
    for (int t = threadIdx.x; t < 32 * 32; t += 256) {
        int k = t / 32, j = t % 32;
        Wd[t] = W1[(size_t)(37 + k) * 32 + j];
        Wg[t] = W1[(size_t)(69 + k) * 32 + j];
    }
    __syncthreads();

    int gid = blockIdx.x * 256 + threadIdx.x;
    int seg = gid / 32;
    int j   = gid % 32;
    if (seg >= nd + no) return;

    const float* srow;
    const float* Wl;
    float acc;
    float* outp;
    if (seg < nd) {
        srow = dag_sum + (size_t)seg * 32;
        Wl = Wd; acc = 0.f;
        outp = dag_h1 + (size_t)seg * 32 + j;
    } else {
        srow = glob_sum + (size_t)(seg - nd) * 32;
        Wl = Wg; acc = b1[j];
        outp = glob_h1 + (size_t)(seg - nd) * 32 + j;
    }
#pragma unroll
    for (int k = 0; k < 32; k++)
        acc = fmaf(srow[k], Wl[k * 32 + j], acc);
    *outp = acc;
}

// ---------------------------------------------------------------------------
// K3 helper: one emb float4 -> 128 FMAs into h1 (scalar weights, SGPR operand)
// ---------------------------------------------------------------------------
__device__ __forceinline__ void emb4(const float4 e, const int kbase,
                                     const float* __restrict__ W1,
                                     float (&h1)[32])
{
    const float c[4] = {e.x, e.y, e.z, e.w};
#pragma unroll
    for (int kk = 0; kk < 4; kk++) {
#pragma unroll
        for (int j = 0; j < 32; j++)
            h1[j] = fmaf(c[kk], W1[(kbase + kk) * 32 + j], h1[j]);
    }
}

// ---------------------------------------------------------------------------
// K3: main MLP, persistent grid-stride with explicit software pipeline.
// Round-6 stall budget: each wave ~90% stalled -- nearly every vector load
// fully latency-exposed (compiler lookahead at VGPR 36-44 covers nothing,
// 4-wave TLP insufficient). Fix: loads for node n+1 issued mid-compute of
// node n (>=1600 FMA cycles cover ~900cy HBM); gathers for node n issued in
// two 32-VGPR halves, folded mid/end of layer 1. Loads cannot be sunk below
// uses by the compiler, so this pipeline is structural. #pragma unroll 1
// prevents the round-2 over-hoist/spill failure. No barrier in the loop;
// per-thread online softmax (m,s) across iterations, one reduce at the end.
// All weights on the scalar path (round-1 proven best).
// ---------------------------------------------------------------------------
__global__ __launch_bounds__(BLK) void mlp_score_kernel(
    const float* __restrict__ x, const float* __restrict__ emb,
    const float* __restrict__ dag_h1, const float* __restrict__ glob_h1,
    const int* __restrict__ dag_ids, const int* __restrict__ obs_ids,
    const int* __restrict__ mask,
    const float* __restrict__ W1, const float* __restrict__ W2,
    const float* __restrict__ b2, const float* __restrict__ W3,
    const float* __restrict__ b3, const float* __restrict__ W4,
    const float* __restrict__ b4,
    float* __restrict__ scores, float* __restrict__ blk_m,
    double* __restrict__ blk_s, int N)
{
    const int stride = gridDim.x * BLK;
    int i = blockIdx.x * BLK + threadIdx.x;

    float  m_acc = -INFINITY;
    double s_acc = 0.0;

    bool valid = (i < N);
    const int idx0 = valid ? i : 0;

    // --- prologue: load node 0's inputs ---
    int d_  = dag_ids[idx0];
    int o_  = obs_ids[idx0];
    int mk_ = mask[idx0];
    const float* xr0 = x + (size_t)idx0 * 5;
    float x0_ = xr0[0], x1_ = xr0[1], x2_ = xr0[2], x3_ = xr0[3], x4_ = xr0[4];
    const float4* er0 = (const float4*)(emb + (size_t)idx0 * 32);
    float4 e0_ = er0[0], e1_ = er0[1], e2_ = er0[2], e3_ = er0[3],
           e4_ = er0[4], e5_ = er0[5], e6_ = er0[6], e7_ = er0[7];

#pragma unroll 1
    for (; valid; ) {
        const int  inext = i + stride;
        const bool vnext = (inext < N);
        const int  idxn  = vnext ? inext : i;

        // --- 1. issue gather half A (h1[0..15] partials; L2-resident) ---
        const float4* dh = (const float4*)(dag_h1 + (size_t)d_ * 32);
        const float4* gh = (const float4*)(glob_h1 + (size_t)o_ * 32);
        float4 a0 = dh[0], a1 = dh[1], a2 = dh[2], a3 = dh[3];
        float4 p0 = gh[0], p1 = gh[1], p2 = gh[2], p3 = gh[3];

        // --- 2. layer 1 x-phase (k=0..4): 160 FMA covers gather A ---
        float h1[32];
#pragma unroll
        for (int j = 0; j < 32; j++) h1[j] = x0_ * W1[j];
#pragma unroll
        for (int j = 0; j < 32; j++) h1[j] = fmaf(x1_, W1[32 + j], h1[j]);
#pragma unroll
        for (int j = 0; j < 32; j++) h1[j] = fmaf(x2_, W1[64 + j], h1[j]);
#pragma unroll
        for (int j = 0; j < 32; j++) h1[j] = fmaf(x3_, W1[96 + j], h1[j]);
#pragma unroll
        for (int j = 0; j < 32; j++) h1[j] = fmaf(x4_, W1[128 + j], h1[j]);

        // --- 3. emb chunks 0..3 (512 FMA) ---
        emb4(e0_, 5,  W1, h1);
        emb4(e1_, 9,  W1, h1);
        emb4(e2_, 13, W1, h1);
        emb4(e3_, 17, W1, h1);

        // --- 4. fold gather A (frees its 32 VGPRs) ---
#pragma unroll
        for (int c = 0; c < 4; c++) {
            h1[0  + c] += ((const float*)&a0)[c] + ((const float*)&p0)[c];
            h1[4  + c] += ((const float*)&a1)[c] + ((const float*)&p1)[c];
            h1[8  + c] += ((const float*)&a2)[c] + ((const float*)&p2)[c];
            h1[12 + c] += ((const float*)&a3)[c] + ((const float*)&p3)[c];
        }

        // --- 5. issue gather half B (reuses the freed registers) ---
        float4 b0v = dh[4], b1v = dh[5], b2v = dh[6], b3v = dh[7];
        float4 q0  = gh[4], q1  = gh[5], q2  = gh[6], q3  = gh[7];

        // --- 6. issue next node's scalar loads (ids/mask/x) ---
        const int nd_ = dag_ids[idxn];
        const int no_ = obs_ids[idxn];
        const int nmk = mask[idxn];
        const float* nxr = x + (size_t)idxn * 5;
        const float nx0 = nxr[0], nx1 = nxr[1], nx2 = nxr[2],
                    nx3 = nxr[3], nx4 = nxr[4];

        // --- 7. emb chunks 4..7 (512 FMA): covers gather B + next scalars ---
        emb4(e4_, 21, W1, h1);
        emb4(e5_, 25, W1, h1);
        emb4(e6_, 29, W1, h1);
        emb4(e7_, 33, W1, h1);

        // --- 8. fold gather B ---
#pragma unroll
        for (int c = 0; c < 4; c++) {
            h1[16 + c] += ((const float*)&b0v)[c] + ((const float*)&q0)[c];
            h1[20 + c] += ((const float*)&b1v)[c] + ((const float*)&q1)[c];
            h1[24 + c] += ((const float*)&b2v)[c] + ((const float*)&q2)[c];
            h1[28 + c] += ((const float*)&b3v)[c] + ((const float*)&q3)[c];
        }

        // --- 9. issue next node's emb loads: covered by layers 2-4 (~1600cy) ---
        const float4* ner = (const float4*)(emb + (size_t)idxn * 32);
        const float4 ne0 = ner[0], ne1 = ner[1], ne2 = ner[2], ne3 = ner[3],
                     ne4 = ner[4], ne5 = ner[5], ne6 = ner[6], ne7 = ner[7];

        // --- 10. ReLU + layers 2..4 (scalar weights) ---
#pragma unroll
        for (int j = 0; j < 32; j++) h1[j] = fmaxf(h1[j], 0.f);

        float h2[16];
#pragma unroll
        for (int j = 0; j < 16; j++) h2[j] = b2[j];
#pragma unroll
        for (int k = 0; k < 32; k++) {
            const float v = h1[k];
#pragma unroll
            for (int j = 0; j < 16; j++)
                h2[j] = fmaf(v, W2[k * 16 + j], h2[j]);
        }
#pragma unroll
        for (int j = 0; j < 16; j++) h2[j] = fmaxf(h2[j], 0.f);

        float h3[8];
#pragma unroll
        for (int j = 0; j < 8; j++) h3[j] = b3[j];
#pragma unroll
        for (int k = 0; k < 16; k++) {
            const float v = h2[k];
#pragma unroll
            for (int j = 0; j < 8; j++)
                h3[j] = fmaf(v, W3[k * 8 + j], h3[j]);
        }
#pragma unroll
        for (int j = 0; j < 8; j++) h3[j] = fmaxf(h3[j], 0.f);

        float sv = b4[0];
#pragma unroll
        for (int k = 0; k < 8; k++) sv = fmaf(h3[k], W4[k], sv);

        // --- 11. score store + online softmax accumulate ---
        const bool live = (mk_ != 0);
        scores[i] = live ? sv : -FLT_MAX;
        if (live) {
            if (sv <= m_acc) {
                s_acc += (double)expf(sv - m_acc);
            } else {
                s_acc = s_acc * (double)expf(m_acc - sv) + 1.0;
                m_acc = sv;
            }
        }

        // --- 12. rotate pipeline registers ---
        d_ = nd_; o_ = no_; mk_ = nmk;
        x0_ = nx0; x1_ = nx1; x2_ = nx2; x3_ = nx3; x4_ = nx4;
        e0_ = ne0; e1_ = ne1; e2_ = ne2; e3_ = ne3;
        e4_ = ne4; e5_ = ne5; e6_ = ne6; e7_ = ne7;
        i = inext; valid = vnext;
    }

    // --- final block (m, s) reduction: wave shuffle, then tiny LDS merge ---
    float  m  = m_acc;
    double sd = s_acc;
#pragma unroll
    for (int off = 32; off > 0; off >>= 1) {
        float  mo = __shfl_down(m, off);
        double so = __shfl_down(sd, off);
        float M = fmaxf(m, mo);
        double out = 0.0;
        if (m  > -INFINITY) out += sd * (double)expf(m  - M);
        if (mo > -INFINITY) out += so * (double)expf(mo - M);
        m = M; sd = out;
    }
    __shared__ float  mw[BLK / 64];
    __shared__ double sw[BLK / 64];
    const int lane = threadIdx.x & 63, wid = threadIdx.x >> 6;
    if (lane == 0) { mw[wid] = m; sw[wid] = sd; }
    __syncthreads();
    if (threadIdx.x == 0) {
        float M = mw[0]; double S = sw[0];
#pragma unroll
        for (int w = 1; w < BLK / 64; w++) {
            float mb = mw[w]; double sb = sw[w];
            float Mn = fmaxf(M, mb);
            double out = 0.0;
            if (M  > -INFINITY) out += S  * (double)expf(M  - Mn);
            if (mb > -INFINITY) out += sb * (double)expf(mb - Mn);
            M = Mn; S = out;
        }
        blk_m[blockIdx.x] = M;
        blk_s[blockIdx.x] = S;
    }
}

// ---------------------------------------------------------------------------
// K4: merge per-block (m, s) pairs -> gmax, Z. One block.
// ---------------------------------------------------------------------------
__global__ __launch_bounds__(1024) void merge_kernel(
    const float* __restrict__ bm, const double* __restrict__ bs, int n,
    float* __restrict__ gmax, double* __restrict__ Z)
{
    float m = -INFINITY;
    double s = 0.0;
    for (int i = threadIdx.x; i < n; i += 1024) {
        float mb = bm[i]; double sb = bs[i];
        float M = fmaxf(m, mb);
        double out = 0.0;
        if (m  > -INFINITY) out += s  * (double)expf(m  - M);
        if (mb > -INFINITY) out += sb * (double)expf(mb - M);
        m = M; s = out;
    }
    __shared__ float  mred[1024];
    __shared__ double sred[1024];
    mred[threadIdx.x] = m;
    sred[threadIdx.x] = s;
    __syncthreads();
    for (int off = 512; off > 0; off >>= 1) {
        if (threadIdx.x < off) {
            float ma = mred[threadIdx.x], mb = mred[threadIdx.x + off];
            double sa = sred[threadIdx.x], sb = sred[threadIdx.x + off];
            float M = fmaxf(ma, mb);
            double out = 0.0;
            if (ma > -INFINITY) out += sa * (double)expf(ma - M);
            if (mb > -INFINITY) out += sb * (double)expf(mb - M);
            mred[threadIdx.x] = M;
            sred[threadIdx.x] = out;
        }
        __syncthreads();
    }
    if (threadIdx.x == 0) { *gmax = mred[0]; *Z = sred[0]; }
}

// ---------------------------------------------------------------------------
// K5: finalize out[i] = exp(s - gmax) / Z  (masked -FLT_MAX -> exactly 0).
// ---------------------------------------------------------------------------
__global__ __launch_bounds__(BLK) void finalize_kernel(
    const float* __restrict__ scores, int N,
    const float* __restrict__ gmaxp, const double* __restrict__ Zp,
    float* __restrict__ outp)
{
    const float gm = *gmaxp;
    const float rZ = (float)(1.0 / *Zp);
    int i = blockIdx.x * BLK + threadIdx.x;
    if (i < N) outp[i] = expf(scores[i] - gm) * rZ;
}

// ---------------------------------------------------------------------------
extern "C" void kernel_launch(void* const* d_in, const int* in_sizes, int n_in,
                              void* d_out, int out_size, void* d_ws, size_t ws_size,
                              hipStream_t stream)
{
    const float* x        = (const float*)d_in[0];
    const float* emb      = (const float*)d_in[1];
    const float* dag_sum  = (const float*)d_in[2];
    const float* glob_sum = (const float*)d_in[3];
    const int*   dag_cnt  = (const int*)d_in[4];
    const int*   obs_cnt  = (const int*)d_in[5];
    const int*   mask     = (const int*)d_in[6];   // bool staged as int32
    const float* W1 = (const float*)d_in[7];
    const float* b1 = (const float*)d_in[8];
    const float* W2 = (const float*)d_in[9];
    const float* b2 = (const float*)d_in[10];
    const float* W3 = (const float*)d_in[11];
    const float* b3 = (const float*)d_in[12];
    const float* W4 = (const float*)d_in[13];
    const float* b4 = (const float*)d_in[14];
    float* outp = (float*)d_out;

    const int N  = in_sizes[0] / 5;   // 2,000,000
    const int nd = in_sizes[4];       // 20,000
    const int no = in_sizes[5];       // 1,000

    // --- workspace layout (16B aligned slices) ---
    char* ws = (char*)d_ws;
    size_t off = 0;
    auto alloc = [&](size_t bytes) {
        void* p = ws + off;
        off += (bytes + 15) & ~(size_t)15;
        return p;
    };
    int*    dag_starts = (int*)   alloc((size_t)(nd + 1) * sizeof(int));
    int*    obs_starts = (int*)   alloc((size_t)(no + 1) * sizeof(int));
    int*    dag_ids    = (int*)   alloc((size_t)N * sizeof(int));
    int*    obs_ids    = (int*)   alloc((size_t)N * sizeof(int));
    float*  dag_h1     = (float*) alloc((size_t)nd * 32 * sizeof(float));
    float*  glob_h1    = (float*) alloc((size_t)no * 32 * sizeof(float));
    float*  scores     = (float*) alloc((size_t)N * sizeof(float));
    float*  blk_m      = (float*) alloc((size_t)K3_BLOCKS * sizeof(float));
    double* blk_s      = (double*)alloc((size_t)K3_BLOCKS * sizeof(double));
    float*  gmax       = (float*) alloc(sizeof(float));
    double* Z          = (double*)alloc(sizeof(double));
    (void)ws_size;

    // K0: prefix scans
    scan2_kernel<<<1, 1024, 0, stream>>>(dag_cnt, nd, obs_cnt, no, dag_starts, obs_starts);

    // K1: expand segment ids to nodes
    expand_ids_kernel<<<nd + no, 128, 0, stream>>>(dag_starts, nd, obs_starts, no, dag_ids, obs_ids);

    // K2: per-segment layer-1 partials
    {
        int total = (nd + no) * 32;
        seg_h1_kernel<<<(total + 255) / 256, 256, 0, stream>>>(
            dag_sum, nd, glob_sum, no, W1, b1, dag_h1, glob_h1);
    }

    // K3: main MLP, persistent grid-stride (software-pipelined)
    mlp_score_kernel<<<K3_BLOCKS, BLK, 0, stream>>>(
        x, emb, dag_h1, glob_h1, dag_ids, obs_ids, mask,
        W1, W2, b2, W3, b3, W4, b4, scores, blk_m, blk_s, N);

    // K4: merge -> gmax, Z
    merge_kernel<<<1, 1024, 0, stream>>>(blk_m, blk_s, K3_BLOCKS, gmax, Z);

    // K5: finalize
    finalize_kernel<<<(N + BLK - 1) / BLK, BLK, 0, stream>>>(scores, N, gmax, Z, outp);
}

// Round 9
// 476.401 us; speedup vs baseline: 1.2800x; 1.2800x over previous
//
#include <hip/hip_runtime.h>
#include <math.h>
#include <float.h>

#define BLK 256

typedef __fp16 half2_t __attribute__((ext_vector_type(2)));

static __device__ __forceinline__ half2_t pkh2(float a, float b)
{
    return __builtin_amdgcn_cvt_pkrtz(a, b);   // v_cvt_pkrtz_f16_f32 -> V2h
}

static __device__ __forceinline__ float fdot2(half2_t a, half2_t b, float c)
{
#if __has_builtin(__builtin_amdgcn_fdot2)
    return __builtin_amdgcn_fdot2(a, b, c, false);   // v_dot2_f32_f16: 2 MACs/inst
#else
    return fmaf((float)a[0], (float)b[0], fmaf((float)a[1], (float)b[1], c));
#endif
}

// ---------------------------------------------------------------------------
// K0: fast exclusive scan of both count arrays. One block, 1024 threads.
// ---------------------------------------------------------------------------
__device__ __forceinline__ void scan_one(const int* __restrict__ cnt, int n,
                                         int* __restrict__ starts, int* wsum)
{
    const int t = threadIdx.x;
    const int chunk = (n + 1023) / 1024;
    const int base = t * chunk;

    int sum = 0;
    for (int k = 0; k < chunk; k++) {
        int idx = base + k;
        if (idx < n) sum += cnt[idx];
    }

    const int lane = t & 63, wid = t >> 6;
    int v = sum;
#pragma unroll
    for (int off = 1; off < 64; off <<= 1) {
        int y = __shfl_up(v, off);
        if (lane >= off) v += y;
    }
    if (lane == 63) wsum[wid] = v;
    __syncthreads();
    if (wid == 0) {
        int w = (lane < 16) ? wsum[lane] : 0;
#pragma unroll
        for (int off = 1; off < 16; off <<= 1) {
            int y = __shfl_up(w, off);
            if (lane >= off) w += y;
        }
        if (lane < 16) wsum[lane] = w;
    }
    __syncthreads();

    int thr_excl = ((wid > 0) ? wsum[wid - 1] : 0) + v - sum;
    int run = thr_excl;
    for (int k = 0; k < chunk; k++) {
        int idx = base + k;
        if (idx < n) { starts[idx] = run; run += cnt[idx]; }
    }
    if (t == 0) starts[n] = wsum[15];
    __syncthreads();
}

__global__ __launch_bounds__(1024) void scan2_kernel(
    const int* __restrict__ dag_cnt, int nd,
    const int* __restrict__ obs_cnt, int no,
    int* __restrict__ dag_starts, int* __restrict__ obs_starts)
{
    __shared__ int wsum[16];
    scan_one(dag_cnt, nd, dag_starts, wsum);
    scan_one(obs_cnt, no, obs_starts, wsum);
}

// ---------------------------------------------------------------------------
// K1: expand segment ids to per-node arrays (one block per segment).
// ---------------------------------------------------------------------------
__global__ __launch_bounds__(128) void expand_ids_kernel(
    const int* __restrict__ dag_starts, int nd,
    const int* __restrict__ obs_starts, int no,
    int* __restrict__ dag_ids, int* __restrict__ obs_ids)
{
    int seg = blockIdx.x;
    if (seg < nd) {
        int s = dag_starts[seg], e = dag_starts[seg + 1];
        for (int i = s + threadIdx.x; i < e; i += 128) dag_ids[i] = seg;
    } else {
        int g = seg - nd;
        int s = obs_starts[g], e = obs_starts[g + 1];
        for (int i = s + threadIdx.x; i < e; i += 128) obs_ids[i] = g;
    }
}

// ---------------------------------------------------------------------------
// K2: per-segment layer-1 partials (dag rows 37..68 no bias; glob rows 69..100 +b1).
// These stay FULL FP32 (64 of 101 input dims carry no fp16 error).
// ---------------------------------------------------------------------------
__global__ __launch_bounds__(256) void seg_h1_kernel(
    const float* __restrict__ dag_sum, int nd,
    const float* __restrict__ glob_sum, int no,
    const float* __restrict__ W1, const float* __restrict__ b1,
    float* __restrict__ dag_h1, float* __restrict__ glob_h1)
{
    __shared__ float Wd[32 * 32];
    __shared__ float Wg[32 * 32];
    for (int t = threadIdx.x; t < 32 * 32; t += 256) {
        int k = t / 32, j = t % 32;
        Wd[t] = W1[(size_t)(37 + k) * 32 + j];
        Wg[t] = W1[(size_t)(69 + k) * 32 + j];
    }
    __syncthreads();

    int gid = blockIdx.x * 256 + threadIdx.x;
    int seg = gid / 32;
    int j   = gid % 32;
    if (seg >= nd + no) return;

    const float* srow;
    const float* Wl;
    float acc;
    float* outp;
    if (seg < nd) {
        srow = dag_sum + (size_t)seg * 32;
        Wl = Wd; acc = 0.f;
        outp = dag_h1 + (size_t)seg * 32 + j;
    } else {
        srow = glob_sum + (size_t)(seg - nd) * 32;
        Wl = Wg; acc = b1[j];
        outp = glob_h1 + (size_t)(seg - nd) * 32 + j;
    }
#pragma unroll
    for (int k = 0; k < 32; k++)
        acc = fmaf(srow[k], Wl[k * 32 + j], acc);
    *outp = acc;
}

// ---------------------------------------------------------------------------
// K2b: pack MLP weights into half2 pairs (row 2p with row 2p+1).
//   W1p: rows 0..36 of W1 (x + emb part) -> 19 pairs x 32  (row 37 slot = 0)
//   W2p: 16 pairs x 16 ; W3p: 8 pairs x 8 ; W4p: 4 pairs
// Halves both the VALU MAC count (fdot2) and the scalar s_load stream.
// ---------------------------------------------------------------------------
__global__ __launch_bounds__(256) void pack_weights_kernel(
    const float* __restrict__ W1, const float* __restrict__ W2,
    const float* __restrict__ W3, const float* __restrict__ W4,
    half2_t* __restrict__ W1p, half2_t* __restrict__ W2p,
    half2_t* __restrict__ W3p, half2_t* __restrict__ W4p)
{
    for (int t = threadIdx.x; t < 19 * 32; t += 256) {
        int p = t / 32, j = t % 32;
        int r0 = 2 * p, r1 = 2 * p + 1;
        float lo = W1[(size_t)r0 * 32 + j];
        float hi = (r1 <= 36) ? W1[(size_t)r1 * 32 + j] : 0.f;
        W1p[t] = pkh2(lo, hi);
    }
    for (int t = threadIdx.x; t < 16 * 16; t += 256) {
        int p = t / 16, j = t % 16;
        W2p[t] = pkh2(W2[(size_t)(2 * p) * 16 + j], W2[(size_t)(2 * p + 1) * 16 + j]);
    }
    for (int t = threadIdx.x; t < 8 * 8; t += 256) {
        int p = t / 8, j = t % 8;
        W3p[t] = pkh2(W3[(size_t)(2 * p) * 8 + j], W3[(size_t)(2 * p + 1) * 8 + j]);
    }
    if (threadIdx.x < 4)
        W4p[threadIdx.x] = pkh2(W4[2 * threadIdx.x], W4[2 * threadIdx.x + 1]);
}

// ---------------------------------------------------------------------------
// K3: main MLP, fp16-dot2 form. ONE node per thread (round-1 structure: the
// only one that measured 154us; rounds 2-7 alternatives all regressed).
// Round-7 insight: K3 is VALU-ISSUE-bound (pure-FMA floor = 99us; round-1 ran
// 78% busy at 154us). v_dot2_f32_f16 does 2 MACs/inst at VALU rate with fp32
// accumulate -> MAC instruction count halves. Gathered dag/glob partials are
// folded in fp32 AFTER the dot block (round-1 latency pattern).
// ---------------------------------------------------------------------------
__global__ __launch_bounds__(BLK) void mlp_score_kernel(
    const float* __restrict__ x, const float* __restrict__ emb,
    const float* __restrict__ dag_h1, const float* __restrict__ glob_h1,
    const int* __restrict__ dag_ids, const int* __restrict__ obs_ids,
    const int* __restrict__ mask,
    const half2_t* __restrict__ W1p, const half2_t* __restrict__ W2p,
    const half2_t* __restrict__ W3p, const half2_t* __restrict__ W4p,
    const float* __restrict__ b2, const float* __restrict__ b3,
    const float* __restrict__ b4,
    float* __restrict__ scores, float* __restrict__ blk_m,
    double* __restrict__ blk_s, int N)
{
    const int i0 = blockIdx.x * BLK + threadIdx.x;
    const bool valid = (i0 < N);
    const int i = valid ? i0 : (N - 1);   // clamp: loads safe, result discarded

    // --- ids first (gathers depend on them) ---
    const int d  = dag_ids[i];
    const int o  = obs_ids[i];
    const int mk = mask[i];

    // --- issue gathers; consumed AFTER the L1 dot block (~650 inst cover) ---
    const float4* dh = (const float4*)(dag_h1 + (size_t)d * 32);
    const float4* gh = (const float4*)(glob_h1 + (size_t)o * 32);
    float4 dq0 = dh[0], dq1 = dh[1], dq2 = dh[2], dq3 = dh[3],
           dq4 = dh[4], dq5 = dh[5], dq6 = dh[6], dq7 = dh[7];
    float4 gq0 = gh[0], gq1 = gh[1], gq2 = gh[2], gq3 = gh[3],
           gq4 = gh[4], gq5 = gh[5], gq6 = gh[6], gq7 = gh[7];

    // --- x + emb loads -> fp16 pair registers (38 values incl. zero pad) ---
    const float* xr = x + (size_t)i * 5;
    float in_[38];
    in_[0] = xr[0]; in_[1] = xr[1]; in_[2] = xr[2]; in_[3] = xr[3]; in_[4] = xr[4];
    const float4* er = (const float4*)(emb + (size_t)i * 32);
#pragma unroll
    for (int q = 0; q < 8; q++) {
        float4 e = er[q];
        in_[5 + 4 * q + 0] = e.x;
        in_[5 + 4 * q + 1] = e.y;
        in_[5 + 4 * q + 2] = e.z;
        in_[5 + 4 * q + 3] = e.w;
    }
    in_[37] = 0.f;

    half2_t ip[19];
#pragma unroll
    for (int p = 0; p < 19; p++) ip[p] = pkh2(in_[2 * p], in_[2 * p + 1]);

    // --- layer 1: 19 dot2-steps x 32 outputs (weights scalar -> SGPR) ---
    float h1[32];
#pragma unroll
    for (int j = 0; j < 32; j++) h1[j] = fdot2(ip[0], W1p[j], 0.f);
#pragma unroll
    for (int p = 1; p < 19; p++) {
#pragma unroll
        for (int j = 0; j < 32; j++)
            h1[j] = fdot2(ip[p], W1p[p * 32 + j], h1[j]);
    }

    // --- fold gathered fp32 partials (b1 inside glob_h1) + ReLU ---
#pragma unroll
    for (int c = 0; c < 4; c++) {
        h1[0  + c] += ((const float*)&dq0)[c] + ((const float*)&gq0)[c];
        h1[4  + c] += ((const float*)&dq1)[c] + ((const float*)&gq1)[c];
        h1[8  + c] += ((const float*)&dq2)[c] + ((const float*)&gq2)[c];
        h1[12 + c] += ((const float*)&dq3)[c] + ((const float*)&gq3)[c];
        h1[16 + c] += ((const float*)&dq4)[c] + ((const float*)&gq4)[c];
        h1[20 + c] += ((const float*)&dq5)[c] + ((const float*)&gq5)[c];
        h1[24 + c] += ((const float*)&dq6)[c] + ((const float*)&gq6)[c];
        h1[28 + c] += ((const float*)&dq7)[c] + ((const float*)&gq7)[c];
    }
#pragma unroll
    for (int j = 0; j < 32; j++) h1[j] = fmaxf(h1[j], 0.f);

    // --- layer 2: 32 -> 16 ---
    half2_t hp[16];
#pragma unroll
    for (int k = 0; k < 16; k++) hp[k] = pkh2(h1[2 * k], h1[2 * k + 1]);
    float h2[16];
#pragma unroll
    for (int j = 0; j < 16; j++) h2[j] = b2[j];
#pragma unroll
    for (int p = 0; p < 16; p++) {
#pragma unroll
        for (int j = 0; j < 16; j++)
            h2[j] = fdot2(hp[p], W2p[p * 16 + j], h2[j]);
    }
#pragma unroll
    for (int j = 0; j < 16; j++) h2[j] = fmaxf(h2[j], 0.f);

    // --- layer 3: 16 -> 8 ---
    half2_t h2p[8];
#pragma unroll
    for (int k = 0; k < 8; k++) h2p[k] = pkh2(h2[2 * k], h2[2 * k + 1]);
    float h3[8];
#pragma unroll
    for (int j = 0; j < 8; j++) h3[j] = b3[j];
#pragma unroll
    for (int p = 0; p < 8; p++) {
#pragma unroll
        for (int j = 0; j < 8; j++)
            h3[j] = fdot2(h2p[p], W3p[p * 8 + j], h3[j]);
    }
#pragma unroll
    for (int j = 0; j < 8; j++) h3[j] = fmaxf(h3[j], 0.f);

    // --- layer 4 ---
    half2_t h3p[4];
#pragma unroll
    for (int k = 0; k < 4; k++) h3p[k] = pkh2(h3[2 * k], h3[2 * k + 1]);
    float s = b4[0];
#pragma unroll
    for (int p = 0; p < 4; p++) s = fdot2(h3p[p], W4p[p], s);

    const bool live = valid && (mk != 0);
    if (valid) scores[i0] = live ? s : -FLT_MAX;

    // --- block (m, sum) merge: wave shuffle reduce, then tiny LDS merge ---
    float  m  = live ? s : -INFINITY;
    double sd = live ? 1.0 : 0.0;
#pragma unroll
    for (int off = 32; off > 0; off >>= 1) {
        float  mo = __shfl_down(m, off);
        double so = __shfl_down(sd, off);
        float M = fmaxf(m, mo);
        double out = 0.0;
        if (m  > -INFINITY) out += sd * (double)expf(m  - M);
        if (mo > -INFINITY) out += so * (double)expf(mo - M);
        m = M; sd = out;
    }
    __shared__ float  mw[BLK / 64];
    __shared__ double sw[BLK / 64];
    const int lane = threadIdx.x & 63, wid = threadIdx.x >> 6;
    if (lane == 0) { mw[wid] = m; sw[wid] = sd; }
    __syncthreads();
    if (threadIdx.x == 0) {
        float M = mw[0]; double S = sw[0];
#pragma unroll
        for (int w = 1; w < BLK / 64; w++) {
            float mb = mw[w]; double sb = sw[w];
            float Mn = fmaxf(M, mb);
            double out = 0.0;
            if (M  > -INFINITY) out += S  * (double)expf(M  - Mn);
            if (mb > -INFINITY) out += sb * (double)expf(mb - Mn);
            M = Mn; S = out;
        }
        blk_m[blockIdx.x] = M;
        blk_s[blockIdx.x] = S;
    }
}

// ---------------------------------------------------------------------------
// K4: merge per-block (m, s) pairs -> gmax, Z. One block.
// ---------------------------------------------------------------------------
__global__ __launch_bounds__(1024) void merge_kernel(
    const float* __restrict__ bm, const double* __restrict__ bs, int n,
    float* __restrict__ gmax, double* __restrict__ Z)
{
    float m = -INFINITY;
    double s = 0.0;
    for (int i = threadIdx.x; i < n; i += 1024) {
        float mb = bm[i]; double sb = bs[i];
        float M = fmaxf(m, mb);
        double out = 0.0;
        if (m  > -INFINITY) out += s  * (double)expf(m  - M);
        if (mb > -INFINITY) out += sb * (double)expf(mb - M);
        m = M; s = out;
    }
    __shared__ float  mred[1024];
    __shared__ double sred[1024];
    mred[threadIdx.x] = m;
    sred[threadIdx.x] = s;
    __syncthreads();
    for (int off = 512; off > 0; off >>= 1) {
        if (threadIdx.x < off) {
            float ma = mred[threadIdx.x], mb = mred[threadIdx.x + off];
            double sa = sred[threadIdx.x], sb = sred[threadIdx.x + off];
            float M = fmaxf(ma, mb);
            double out = 0.0;
            if (ma > -INFINITY) out += sa * (double)expf(ma - M);
            if (mb > -INFINITY) out += sb * (double)expf(mb - M);
            mred[threadIdx.x] = M;
            sred[threadIdx.x] = out;
        }
        __syncthreads();
    }
    if (threadIdx.x == 0) { *gmax = mred[0]; *Z = sred[0]; }
}

// ---------------------------------------------------------------------------
// K5: finalize out[i] = exp(s - gmax) / Z  (masked -FLT_MAX -> exactly 0).
// ---------------------------------------------------------------------------
__global__ __launch_bounds__(BLK) void finalize_kernel(
    const float* __restrict__ scores, int N,
    const float* __restrict__ gmaxp, const double* __restrict__ Zp,
    float* __restrict__ outp)
{
    const float gm = *gmaxp;
    const float rZ = (float)(1.0 / *Zp);
    int i = blockIdx.x * BLK + threadIdx.x;
    if (i < N) outp[i] = expf(scores[i] - gm) * rZ;
}

// ---------------------------------------------------------------------------
extern "C" void kernel_launch(void* const* d_in, const int* in_sizes, int n_in,
                              void* d_out, int out_size, void* d_ws, size_t ws_size,
                              hipStream_t stream)
{
    const float* x        = (const float*)d_in[0];
    const float* emb      = (const float*)d_in[1];
    const float* dag_sum  = (const float*)d_in[2];
    const float* glob_sum = (const float*)d_in[3];
    const int*   dag_cnt  = (const int*)d_in[4];
    const int*   obs_cnt  = (const int*)d_in[5];
    const int*   mask     = (const int*)d_in[6];   // bool staged as int32
    const float* W1 = (const float*)d_in[7];
    const float* b1 = (const float*)d_in[8];
    const float* W2 = (const float*)d_in[9];
    const float* b2 = (const float*)d_in[10];
    const float* W3 = (const float*)d_in[11];
    const float* b3 = (const float*)d_in[12];
    const float* W4 = (const float*)d_in[13];
    const float* b4 = (const float*)d_in[14];
    float* outp = (float*)d_out;

    const int N  = in_sizes[0] / 5;   // 2,000,000
    const int nd = in_sizes[4];       // 20,000
    const int no = in_sizes[5];       // 1,000

    const int main_blocks = (N + BLK - 1) / BLK;   // 7813

    // --- workspace layout (16B aligned slices) ---
    char* ws = (char*)d_ws;
    size_t off = 0;
    auto alloc = [&](size_t bytes) {
        void* p = ws + off;
        off += (bytes + 15) & ~(size_t)15;
        return p;
    };
    int*     dag_starts = (int*)    alloc((size_t)(nd + 1) * sizeof(int));
    int*     obs_starts = (int*)    alloc((size_t)(no + 1) * sizeof(int));
    int*     dag_ids    = (int*)    alloc((size_t)N * sizeof(int));
    int*     obs_ids    = (int*)    alloc((size_t)N * sizeof(int));
    float*   dag_h1     = (float*)  alloc((size_t)nd * 32 * sizeof(float));
    float*   glob_h1    = (float*)  alloc((size_t)no * 32 * sizeof(float));
    float*   scores     = (float*)  alloc((size_t)N * sizeof(float));
    float*   blk_m      = (float*)  alloc((size_t)main_blocks * sizeof(float));
    double*  blk_s      = (double*) alloc((size_t)main_blocks * sizeof(double));
    float*   gmax       = (float*)  alloc(sizeof(float));
    double*  Z          = (double*) alloc(sizeof(double));
    half2_t* W1p        = (half2_t*)alloc((size_t)19 * 32 * sizeof(half2_t));
    half2_t* W2p        = (half2_t*)alloc((size_t)16 * 16 * sizeof(half2_t));
    half2_t* W3p        = (half2_t*)alloc((size_t)8 * 8 * sizeof(half2_t));
    half2_t* W4p        = (half2_t*)alloc((size_t)4 * sizeof(half2_t));
    (void)ws_size;

    // K0: prefix scans
    scan2_kernel<<<1, 1024, 0, stream>>>(dag_cnt, nd, obs_cnt, no, dag_starts, obs_starts);

    // K2b: pack weights to half2 (independent of K0/K1)
    pack_weights_kernel<<<1, 256, 0, stream>>>(W1, W2, W3, W4, W1p, W2p, W3p, W4p);

    // K1: expand segment ids to nodes
    expand_ids_kernel<<<nd + no, 128, 0, stream>>>(dag_starts, nd, obs_starts, no, dag_ids, obs_ids);

    // K2: per-segment layer-1 partials (fp32)
    {
        int total = (nd + no) * 32;
        seg_h1_kernel<<<(total + 255) / 256, 256, 0, stream>>>(
            dag_sum, nd, glob_sum, no, W1, b1, dag_h1, glob_h1);
    }

    // K3: main MLP (fp16 dot2) + scores + per-block softmax partials
    mlp_score_kernel<<<main_blocks, BLK, 0, stream>>>(
        x, emb, dag_h1, glob_h1, dag_ids, obs_ids, mask,
        W1p, W2p, W3p, W4p, b2, b3, b4, scores, blk_m, blk_s, N);

    // K4: merge -> gmax, Z
    merge_kernel<<<1, 1024, 0, stream>>>(blk_m, blk_s, main_blocks, gmax, Z);

    // K5: finalize
    finalize_kernel<<<(N + BLK - 1) / BLK, BLK, 0, stream>>>(scores, N, gmax, Z, outp);
}

// Round 10
// 475.906 us; speedup vs baseline: 1.2813x; 1.0010x over previous
//
#include <hip/hip_runtime.h>
#include <math.h>
#include <float.h>

#define BLK 256

typedef __fp16 half2_t __attribute__((ext_vector_type(2)));

static __device__ __forceinline__ half2_t pkh2(float a, float b)
{
    return __builtin_amdgcn_cvt_pkrtz(a, b);   // v_cvt_pkrtz_f16_f32 -> V2h
}

static __device__ __forceinline__ float fdot2(half2_t a, half2_t b, float c)
{
#if __has_builtin(__builtin_amdgcn_fdot2)
    return __builtin_amdgcn_fdot2(a, b, c, false);   // v_dot2_f32_f16: 2 MACs/inst
#else
    return fmaf((float)a[0], (float)b[0], fmaf((float)a[1], (float)b[1], c));
#endif
}

// ---------------------------------------------------------------------------
// K0: fast exclusive scan of both count arrays. One block, 1024 threads.
// ---------------------------------------------------------------------------
__device__ __forceinline__ void scan_one(const int* __restrict__ cnt, int n,
                                         int* __restrict__ starts, int* wsum)
{
    const int t = threadIdx.x;
    const int chunk = (n + 1023) / 1024;
    const int base = t * chunk;

    int sum = 0;
    for (int k = 0; k < chunk; k++) {
        int idx = base + k;
        if (idx < n) sum += cnt[idx];
    }

    const int lane = t & 63, wid = t >> 6;
    int v = sum;
#pragma unroll
    for (int off = 1; off < 64; off <<= 1) {
        int y = __shfl_up(v, off);
        if (lane >= off) v += y;
    }
    if (lane == 63) wsum[wid] = v;
    __syncthreads();
    if (wid == 0) {
        int w = (lane < 16) ? wsum[lane] : 0;
#pragma unroll
        for (int off = 1; off < 16; off <<= 1) {
            int y = __shfl_up(w, off);
            if (lane >= off) w += y;
        }
        if (lane < 16) wsum[lane] = w;
    }
    __syncthreads();

    int thr_excl = ((wid > 0) ? wsum[wid - 1] : 0) + v - sum;
    int run = thr_excl;
    for (int k = 0; k < chunk; k++) {
        int idx = base + k;
        if (idx < n) { starts[idx] = run; run += cnt[idx]; }
    }
    if (t == 0) starts[n] = wsum[15];
    __syncthreads();
}

__global__ __launch_bounds__(1024) void scan2_kernel(
    const int* __restrict__ dag_cnt, int nd,
    const int* __restrict__ obs_cnt, int no,
    int* __restrict__ dag_starts, int* __restrict__ obs_starts)
{
    __shared__ int wsum[16];
    scan_one(dag_cnt, nd, dag_starts, wsum);
    scan_one(obs_cnt, no, obs_starts, wsum);
}

// ---------------------------------------------------------------------------
// K1: expand segment ids to per-node arrays (one block per segment).
// ---------------------------------------------------------------------------
__global__ __launch_bounds__(128) void expand_ids_kernel(
    const int* __restrict__ dag_starts, int nd,
    const int* __restrict__ obs_starts, int no,
    int* __restrict__ dag_ids, int* __restrict__ obs_ids)
{
    int seg = blockIdx.x;
    if (seg < nd) {
        int s = dag_starts[seg], e = dag_starts[seg + 1];
        for (int i = s + threadIdx.x; i < e; i += 128) dag_ids[i] = seg;
    } else {
        int g = seg - nd;
        int s = obs_starts[g], e = obs_starts[g + 1];
        for (int i = s + threadIdx.x; i < e; i += 128) obs_ids[i] = g;
    }
}

// ---------------------------------------------------------------------------
// K2: per-segment layer-1 partials (dag rows 37..68 no bias; glob rows 69..100 +b1).
// These stay FULL FP32 (64 of 101 input dims carry no fp16 error).
// ---------------------------------------------------------------------------
__global__ __launch_bounds__(256) void seg_h1_kernel(
    const float* __restrict__ dag_sum, int nd,
    const float* __restrict__ glob_sum, int no,
    const float* __restrict__ W1, const float* __restrict__ b1,
    float* __restrict__ dag_h1, float* __restrict__ glob_h1)
{
    __shared__ float Wd[32 * 32];
    __shared__ float Wg[32 * 32];
    for (int t = threadIdx.x; t < 32 * 32; t += 256) {
        int k = t / 32, j = t % 32;
        Wd[t] = W1[(size_t)(37 + k) * 32 + j];
        Wg[t] = W1[(size_t)(69 + k) * 32 + j];
    }
    __syncthreads();

    int gid = blockIdx.x * 256 + threadIdx.x;
    int seg = gid / 32;
    int j   = gid % 32;
    if (seg >= nd + no) return;

    const float* srow;
    const float* Wl;
    float acc;
    float* outp;
    if (seg < nd) {
        srow = dag_sum + (size_t)seg * 32;
        Wl = Wd; acc = 0.f;
        outp = dag_h1 + (size_t)seg * 32 + j;
    } else {
        srow = glob_sum + (size_t)(seg - nd) * 32;
        Wl = Wg; acc = b1[j];
        outp = glob_h1 + (size_t)(seg - nd) * 32 + j;
    }
#pragma unroll
    for (int k = 0; k < 32; k++)
        acc = fmaf(srow[k], Wl[k * 32 + j], acc);
    *outp = acc;
}

// ---------------------------------------------------------------------------
// K2b: pack MLP weights into half2 pairs, ALIGNED to the streaming order:
//   W1p pair p covers input pair:
//     p=0:(x0,x1) p=1:(x2,x3) p=2:(x4,ZERO)
//     p=3+2q+c : emb rows, pair (5+2(p-3), 6+2(p-3))  [rows 5..36]
//   -> emb float4 q maps exactly to pairs 3+2q (e.x,e.y) and 4+2q (e.z,e.w).
//   W2p: 16 pairs x 16 ; W3p: 8 pairs x 8 ; W4p: 4 pairs
// ---------------------------------------------------------------------------
__global__ __launch_bounds__(256) void pack_weights_kernel(
    const float* __restrict__ W1, const float* __restrict__ W2,
    const float* __restrict__ W3, const float* __restrict__ W4,
    half2_t* __restrict__ W1p, half2_t* __restrict__ W2p,
    half2_t* __restrict__ W3p, half2_t* __restrict__ W4p)
{
    for (int t = threadIdx.x; t < 19 * 32; t += 256) {
        int p = t / 32, j = t % 32;
        float lo, hi;
        if (p == 0)      { lo = W1[0 * 32 + j];  hi = W1[1 * 32 + j]; }
        else if (p == 1) { lo = W1[2 * 32 + j];  hi = W1[3 * 32 + j]; }
        else if (p == 2) { lo = W1[4 * 32 + j];  hi = 0.f; }
        else {
            int r = 5 + 2 * (p - 3);
            lo = W1[(size_t)r * 32 + j];
            hi = W1[(size_t)(r + 1) * 32 + j];
        }
        W1p[t] = pkh2(lo, hi);
    }
    for (int t = threadIdx.x; t < 16 * 16; t += 256) {
        int p = t / 16, j = t % 16;
        W2p[t] = pkh2(W2[(size_t)(2 * p) * 16 + j], W2[(size_t)(2 * p + 1) * 16 + j]);
    }
    for (int t = threadIdx.x; t < 8 * 8; t += 256) {
        int p = t / 8, j = t % 8;
        W3p[t] = pkh2(W3[(size_t)(2 * p) * 8 + j], W3[(size_t)(2 * p + 1) * 8 + j]);
    }
    if (threadIdx.x < 4)
        W4p[threadIdx.x] = pkh2(W4[2 * threadIdx.x], W4[2 * threadIdx.x + 1]);
}

// ---------------------------------------------------------------------------
// K3: main MLP, fp16-dot2 STREAMING form. Round-9 lesson: materializing
// in_[38]+ip[19]+gathers before compute -> ~150 VGPR peak -> occupancy cliff
// -> one huge front-stall; only -17us. This version restores the round-1
// register-lifetime discipline (VGPR 36 there): gathers folded at h1 INIT,
// each emb float4 packed at its use site, no persistent input arrays.
// dot2 math unchanged (absmax 1.49e-8 proven passing).
// ---------------------------------------------------------------------------
__global__ __launch_bounds__(BLK) void mlp_score_kernel(
    const float* __restrict__ x, const float* __restrict__ emb,
    const float* __restrict__ dag_h1, const float* __restrict__ glob_h1,
    const int* __restrict__ dag_ids, const int* __restrict__ obs_ids,
    const int* __restrict__ mask,
    const half2_t* __restrict__ W1p, const half2_t* __restrict__ W2p,
    const half2_t* __restrict__ W3p, const half2_t* __restrict__ W4p,
    const float* __restrict__ b2, const float* __restrict__ b3,
    const float* __restrict__ b4,
    float* __restrict__ scores, float* __restrict__ blk_m,
    double* __restrict__ blk_s, int N)
{
    const int i0 = blockIdx.x * BLK + threadIdx.x;
    const bool valid = (i0 < N);
    const int i = valid ? i0 : (N - 1);   // clamp: loads safe, result discarded

    // --- ids first (gathers depend on them) ---
    const int d  = dag_ids[i];
    const int o  = obs_ids[i];
    const int mk = mask[i];

    // --- gathers: folded immediately into h1 init (regs die fast) ---
    const float4* dh = (const float4*)(dag_h1 + (size_t)d * 32);
    const float4* gh = (const float4*)(glob_h1 + (size_t)o * 32);

    float h1[32];
#pragma unroll
    for (int q = 0; q < 8; q++) {
        float4 dv = dh[q], gv = gh[q];
        h1[4 * q + 0] = dv.x + gv.x;
        h1[4 * q + 1] = dv.y + gv.y;
        h1[4 * q + 2] = dv.z + gv.z;
        h1[4 * q + 3] = dv.w + gv.w;
    }

    // --- x phase: 3 pairs (x0x1, x2x3, x4|0), weights scalar -> SGPR ---
    const float* xr = x + (size_t)i * 5;
    const float xv0 = xr[0], xv1 = xr[1], xv2 = xr[2], xv3 = xr[3], xv4 = xr[4];
    {
        const half2_t xp0 = pkh2(xv0, xv1);
#pragma unroll
        for (int j = 0; j < 32; j++) h1[j] = fdot2(xp0, W1p[j], h1[j]);
        const half2_t xp1 = pkh2(xv2, xv3);
#pragma unroll
        for (int j = 0; j < 32; j++) h1[j] = fdot2(xp1, W1p[32 + j], h1[j]);
        const half2_t xp2 = pkh2(xv4, 0.f);
#pragma unroll
        for (int j = 0; j < 32; j++) h1[j] = fdot2(xp2, W1p[64 + j], h1[j]);
    }

    // --- emb phase: 8 float4 loads, each -> 2 pairs -> 64 dots, streaming ---
    const float4* er = (const float4*)(emb + (size_t)i * 32);
#pragma unroll
    for (int q = 0; q < 8; q++) {
        const float4 e = er[q];
        const half2_t pa = pkh2(e.x, e.y);
#pragma unroll
        for (int j = 0; j < 32; j++)
            h1[j] = fdot2(pa, W1p[(3 + 2 * q) * 32 + j], h1[j]);
        const half2_t pb = pkh2(e.z, e.w);
#pragma unroll
        for (int j = 0; j < 32; j++)
            h1[j] = fdot2(pb, W1p[(4 + 2 * q) * 32 + j], h1[j]);
    }

#pragma unroll
    for (int j = 0; j < 32; j++) h1[j] = fmaxf(h1[j], 0.f);

    // --- layer 2: 32 -> 16 (pack pairs at use) ---
    float h2[16];
#pragma unroll
    for (int j = 0; j < 16; j++) h2[j] = b2[j];
#pragma unroll
    for (int p = 0; p < 16; p++) {
        const half2_t hp = pkh2(h1[2 * p], h1[2 * p + 1]);
#pragma unroll
        for (int j = 0; j < 16; j++)
            h2[j] = fdot2(hp, W2p[p * 16 + j], h2[j]);
    }
#pragma unroll
    for (int j = 0; j < 16; j++) h2[j] = fmaxf(h2[j], 0.f);

    // --- layer 3: 16 -> 8 ---
    float h3[8];
#pragma unroll
    for (int j = 0; j < 8; j++) h3[j] = b3[j];
#pragma unroll
    for (int p = 0; p < 8; p++) {
        const half2_t hp = pkh2(h2[2 * p], h2[2 * p + 1]);
#pragma unroll
        for (int j = 0; j < 8; j++)
            h3[j] = fdot2(hp, W3p[p * 8 + j], h3[j]);
    }
#pragma unroll
    for (int j = 0; j < 8; j++) h3[j] = fmaxf(h3[j], 0.f);

    // --- layer 4 ---
    float s = b4[0];
#pragma unroll
    for (int p = 0; p < 4; p++) {
        const half2_t hp = pkh2(h3[2 * p], h3[2 * p + 1]);
        s = fdot2(hp, W4p[p], s);
    }

    const bool live = valid && (mk != 0);
    if (valid) scores[i0] = live ? s : -FLT_MAX;

    // --- block (m, sum) merge: wave shuffle reduce, then tiny LDS merge ---
    float  m  = live ? s : -INFINITY;
    double sd = live ? 1.0 : 0.0;
#pragma unroll
    for (int off = 32; off > 0; off >>= 1) {
        float  mo = __shfl_down(m, off);
        double so = __shfl_down(sd, off);
        float M = fmaxf(m, mo);
        double out = 0.0;
        if (m  > -INFINITY) out += sd * (double)expf(m  - M);
        if (mo > -INFINITY) out += so * (double)expf(mo - M);
        m = M; sd = out;
    }
    __shared__ float  mw[BLK / 64];
    __shared__ double sw[BLK / 64];
    const int lane = threadIdx.x & 63, wid = threadIdx.x >> 6;
    if (lane == 0) { mw[wid] = m; sw[wid] = sd; }
    __syncthreads();
    if (threadIdx.x == 0) {
        float M = mw[0]; double S = sw[0];
#pragma unroll
        for (int w = 1; w < BLK / 64; w++) {
            float mb = mw[w]; double sb = sw[w];
            float Mn = fmaxf(M, mb);
            double out = 0.0;
            if (M  > -INFINITY) out += S  * (double)expf(M  - Mn);
            if (mb > -INFINITY) out += sb * (double)expf(mb - Mn);
            M = Mn; S = out;
        }
        blk_m[blockIdx.x] = M;
        blk_s[blockIdx.x] = S;
    }
}

// ---------------------------------------------------------------------------
// K4: merge per-block (m, s) pairs -> gmax, Z. One block.
// ---------------------------------------------------------------------------
__global__ __launch_bounds__(1024) void merge_kernel(
    const float* __restrict__ bm, const double* __restrict__ bs, int n,
    float* __restrict__ gmax, double* __restrict__ Z)
{
    float m = -INFINITY;
    double s = 0.0;
    for (int i = threadIdx.x; i < n; i += 1024) {
        float mb = bm[i]; double sb = bs[i];
        float M = fmaxf(m, mb);
        double out = 0.0;
        if (m  > -INFINITY) out += s  * (double)expf(m  - M);
        if (mb > -INFINITY) out += sb * (double)expf(mb - M);
        m = M; s = out;
    }
    __shared__ float  mred[1024];
    __shared__ double sred[1024];
    mred[threadIdx.x] = m;
    sred[threadIdx.x] = s;
    __syncthreads();
    for (int off = 512; off > 0; off >>= 1) {
        if (threadIdx.x < off) {
            float ma = mred[threadIdx.x], mb = mred[threadIdx.x + off];
            double sa = sred[threadIdx.x], sb = sred[threadIdx.x + off];
            float M = fmaxf(ma, mb);
            double out = 0.0;
            if (ma > -INFINITY) out += sa * (double)expf(ma - M);
            if (mb > -INFINITY) out += sb * (double)expf(mb - M);
            mred[threadIdx.x] = M;
            sred[threadIdx.x] = out;
        }
        __syncthreads();
    }
    if (threadIdx.x == 0) { *gmax = mred[0]; *Z = sred[0]; }
}

// ---------------------------------------------------------------------------
// K5: finalize out[i] = exp(s - gmax) / Z  (masked -FLT_MAX -> exactly 0).
// ---------------------------------------------------------------------------
__global__ __launch_bounds__(BLK) void finalize_kernel(
    const float* __restrict__ scores, int N,
    const float* __restrict__ gmaxp, const double* __restrict__ Zp,
    float* __restrict__ outp)
{
    const float gm = *gmaxp;
    const float rZ = (float)(1.0 / *Zp);
    int i = blockIdx.x * BLK + threadIdx.x;
    if (i < N) outp[i] = expf(scores[i] - gm) * rZ;
}

// ---------------------------------------------------------------------------
extern "C" void kernel_launch(void* const* d_in, const int* in_sizes, int n_in,
                              void* d_out, int out_size, void* d_ws, size_t ws_size,
                              hipStream_t stream)
{
    const float* x        = (const float*)d_in[0];
    const float* emb      = (const float*)d_in[1];
    const float* dag_sum  = (const float*)d_in[2];
    const float* glob_sum = (const float*)d_in[3];
    const int*   dag_cnt  = (const int*)d_in[4];
    const int*   obs_cnt  = (const int*)d_in[5];
    const int*   mask     = (const int*)d_in[6];   // bool staged as int32
    const float* W1 = (const float*)d_in[7];
    const float* b1 = (const float*)d_in[8];
    const float* W2 = (const float*)d_in[9];
    const float* b2 = (const float*)d_in[10];
    const float* W3 = (const float*)d_in[11];
    const float* b3 = (const float*)d_in[12];
    const float* W4 = (const float*)d_in[13];
    const float* b4 = (const float*)d_in[14];
    float* outp = (float*)d_out;

    const int N  = in_sizes[0] / 5;   // 2,000,000
    const int nd = in_sizes[4];       // 20,000
    const int no = in_sizes[5];       // 1,000

    const int main_blocks = (N + BLK - 1) / BLK;   // 7813

    // --- workspace layout (16B aligned slices) ---
    char* ws = (char*)d_ws;
    size_t off = 0;
    auto alloc = [&](size_t bytes) {
        void* p = ws + off;
        off += (bytes + 15) & ~(size_t)15;
        return p;
    };
    int*     dag_starts = (int*)    alloc((size_t)(nd + 1) * sizeof(int));
    int*     obs_starts = (int*)    alloc((size_t)(no + 1) * sizeof(int));
    int*     dag_ids    = (int*)    alloc((size_t)N * sizeof(int));
    int*     obs_ids    = (int*)    alloc((size_t)N * sizeof(int));
    float*   dag_h1     = (float*)  alloc((size_t)nd * 32 * sizeof(float));
    float*   glob_h1    = (float*)  alloc((size_t)no * 32 * sizeof(float));
    float*   scores     = (float*)  alloc((size_t)N * sizeof(float));
    float*   blk_m      = (float*)  alloc((size_t)main_blocks * sizeof(float));
    double*  blk_s      = (double*) alloc((size_t)main_blocks * sizeof(double));
    float*   gmax       = (float*)  alloc(sizeof(float));
    double*  Z          = (double*) alloc(sizeof(double));
    half2_t* W1p        = (half2_t*)alloc((size_t)19 * 32 * sizeof(half2_t));
    half2_t* W2p        = (half2_t*)alloc((size_t)16 * 16 * sizeof(half2_t));
    half2_t* W3p        = (half2_t*)alloc((size_t)8 * 8 * sizeof(half2_t));
    half2_t* W4p        = (half2_t*)alloc((size_t)4 * sizeof(half2_t));
    (void)ws_size;

    // K0: prefix scans
    scan2_kernel<<<1, 1024, 0, stream>>>(dag_cnt, nd, obs_cnt, no, dag_starts, obs_starts);

    // K2b: pack weights to half2 (independent of K0/K1)
    pack_weights_kernel<<<1, 256, 0, stream>>>(W1, W2, W3, W4, W1p, W2p, W3p, W4p);

    // K1: expand segment ids to nodes
    expand_ids_kernel<<<nd + no, 128, 0, stream>>>(dag_starts, nd, obs_starts, no, dag_ids, obs_ids);

    // K2: per-segment layer-1 partials (fp32)
    {
        int total = (nd + no) * 32;
        seg_h1_kernel<<<(total + 255) / 256, 256, 0, stream>>>(
            dag_sum, nd, glob_sum, no, W1, b1, dag_h1, glob_h1);
    }

    // K3: main MLP (fp16 dot2, streaming) + scores + per-block softmax partials
    mlp_score_kernel<<<main_blocks, BLK, 0, stream>>>(
        x, emb, dag_h1, glob_h1, dag_ids, obs_ids, mask,
        W1p, W2p, W3p, W4p, b2, b3, b4, scores, blk_m, blk_s, N);

    // K4: merge -> gmax, Z
    merge_kernel<<<1, 1024, 0, stream>>>(blk_m, blk_s, main_blocks, gmax, Z);

    // K5: finalize
    finalize_kernel<<<(N + BLK - 1) / BLK, BLK, 0, stream>>>(scores, N, gmax, Z, outp);
}